// Round 3
// baseline (164.212 us; speedup 1.0000x reference)
//
#include <hip/hip_runtime.h>
#include <stdint.h>

// Problem constants
#define N_      8
#define IC_     16
#define C1_     2048
#define H_      56
#define W_      56
#define WT_     16            // w-tile per block (tiles at 0,16,32,40; last overlaps)
#define NWT_    4
#define THREADS_ 512
#define ROWU_   10            // LDS row stride in dwords (8 used + 2 pad -> rows 8B-aligned)

// One block = (n, h, 16-wide w-tile). Phase 1: all 2048 conv channels -> LDS (bf16 packed).
// Phase 2: pixel-major gather: 4 lanes per output channel, float4 coalesced stores.
__global__ __launch_bounds__(THREADS_, 4)
void rptn_fused(const float* __restrict__ x,
                const float* __restrict__ W1,
                const float* __restrict__ b1,
                const int* __restrict__ idx,
                float* __restrict__ out)
{
    __shared__ uint32_t s1[C1_ * ROWU_];   // 80 KB -> 2 blocks/CU

    const int tid = threadIdx.x;
    const int b   = blockIdx.x;
    const int n   = b / (H_ * NWT_);
    const int rem = b % (H_ * NWT_);
    const int h   = rem >> 2;
    const int wsel = rem & 3;
    const int w0  = (wsel == 3) ? 40 : wsel * 16;   // 0,16,32,40 (40..55 overlaps 32..47: same values)

    // ---------------- Phase 1: grouped 3x3 conv into LDS (bf16 pairs) ----------------
    #pragma unroll 1
    for (int pass = 0; pass < 4; ++pass) {
        const int c  = pass * THREADS_ + tid;          // out1 channel
        // 64 consecutive c per wave share ci = c/128 -> wave-uniform -> scalar loads
        const int ci = __builtin_amdgcn_readfirstlane(c >> 7);

        float xr[3][WT_ + 2];                           // 3x18 window (SGPR-resident)
        const float* xb = x + (size_t)((n * IC_ + ci) * H_) * W_;
        #pragma unroll
        for (int rr = 0; rr < 3; ++rr) {
            const int r = h - 1 + rr;
            const bool rok = ((unsigned)r < (unsigned)H_);
            #pragma unroll
            for (int cc = 0; cc < WT_ + 2; ++cc) {
                const int col = w0 - 1 + cc;
                const bool ok = rok && ((unsigned)col < (unsigned)W_);
                xr[rr][cc] = ok ? xb[r * W_ + col] : 0.0f;
            }
        }

        float w[9];
        const float* wp = W1 + c * 9;
        #pragma unroll
        for (int k = 0; k < 9; ++k) w[k] = wp[k];
        const float bias = b1[c];

        float acc[WT_];
        #pragma unroll
        for (int p = 0; p < WT_; ++p) acc[p] = bias;

        #pragma unroll
        for (int dr = 0; dr < 3; ++dr) {
            #pragma unroll
            for (int dc = 0; dc < 3; ++dc) {
                const float wk = w[dr * 3 + dc];
                #pragma unroll
                for (int p = 0; p < WT_; ++p)
                    acc[p] = fmaf(xr[dr][p + dc], wk, acc[p]);
            }
        }

        // pack 16 f32 -> 8 dwords of bf16 pairs (RNE)
        uint32_t pk[8];
        #pragma unroll
        for (int k = 0; k < 8; ++k) {
            uint32_t u0 = __float_as_uint(acc[2 * k]);
            uint32_t u1 = __float_as_uint(acc[2 * k + 1]);
            u0 = (u0 + 0x7fffu + ((u0 >> 16) & 1u)) >> 16;
            u1 = (u1 + 0x7fffu + ((u1 >> 16) & 1u)) >> 16;
            pk[k] = u0 | (u1 << 16);
        }
        uint32_t* row = &s1[c * ROWU_];
        *(uint2*)(row + 0) = make_uint2(pk[0], pk[1]);
        *(uint2*)(row + 2) = make_uint2(pk[2], pk[3]);
        *(uint2*)(row + 4) = make_uint2(pk[4], pk[5]);
        *(uint2*)(row + 6) = make_uint2(pk[6], pk[7]);
    }

    __syncthreads();

    // ---------------- Phase 2: pixel-major gather + max + float4 stores ----------------
    // f = linear float4 index over (j, quarter): 2048 channels * 4 = 8192 float4s.
    // 4 consecutive lanes share channel j -> LDS row broadcast + coalesced 64B stores.
    #pragma unroll 4
    for (int it = 0; it < 16; ++it) {
        const int f = it * THREADS_ + tid;
        const int j = f >> 2;                 // output channel
        const int q = f & 3;                  // which float4 of the 16-px tile
        const int4 iv = *(const int4*)(idx + 4 * j);

        const uint2 a = *(const uint2*)(&s1[(iv.x & (C1_ - 1)) * ROWU_ + 2 * q]);
        const uint2 bv = *(const uint2*)(&s1[(iv.y & (C1_ - 1)) * ROWU_ + 2 * q]);
        const uint2 cv = *(const uint2*)(&s1[(iv.z & (C1_ - 1)) * ROWU_ + 2 * q]);
        const uint2 dv = *(const uint2*)(&s1[(iv.w & (C1_ - 1)) * ROWU_ + 2 * q]);

        #define LO_(u) __uint_as_float((u) << 16)
        #define HI_(u) __uint_as_float((u) & 0xffff0000u)
        float4 o;
        o.x = fmaxf(fmaxf(LO_(a.x), LO_(bv.x)), fmaxf(LO_(cv.x), LO_(dv.x)));
        o.y = fmaxf(fmaxf(HI_(a.x), HI_(bv.x)), fmaxf(HI_(cv.x), HI_(dv.x)));
        o.z = fmaxf(fmaxf(LO_(a.y), LO_(bv.y)), fmaxf(LO_(cv.y), LO_(dv.y)));
        o.w = fmaxf(fmaxf(HI_(a.y), HI_(bv.y)), fmaxf(HI_(cv.y), HI_(dv.y)));
        #undef LO_
        #undef HI_

        float* op = out + (size_t)(n * C1_ + j) * (H_ * W_) + h * W_ + w0 + 4 * q;
        *(float4*)op = o;                      // 16B-aligned: w0*4 in {0,64,128,160}
    }
}

extern "C" void kernel_launch(void* const* d_in, const int* in_sizes, int n_in,
                              void* d_out, int out_size, void* d_ws, size_t ws_size,
                              hipStream_t stream)
{
    const float* x   = (const float*)d_in[0];
    const float* W1  = (const float*)d_in[1];
    const float* b1  = (const float*)d_in[2];
    const int* idxp  = (const int*)d_in[3];
    float* out       = (float*)d_out;

    dim3 grid(N_ * H_ * NWT_);   // 1792 blocks
    dim3 block(THREADS_);
    hipLaunchKernelGGL(rptn_fused, grid, block, 0, stream, x, W1, b1, idxp, out);
}